// Round 1
// baseline (281.487 us; speedup 1.0000x reference)
//
#include <hip/hip_runtime.h>

#define EPS 1e-5f

// ---------------- K1: layer1 fused (K=8 GEMM + BN + ReLU) ----------------
// grid = 1024 (one block per output feature j), 256 threads.
// Writes X1 transposed: X1T[j*2048 + r]  (coalesced writes, coalesced GEMM2 A loads)
__global__ __launch_bounds__(256) void k1_layer1(
    const float* __restrict__ G, const float* __restrict__ w1,
    const float* __restrict__ b1, const float* __restrict__ g1,
    const float* __restrict__ be1, float* __restrict__ X1T) {
  int j = blockIdx.x;
  int tid = threadIdx.x;
  float wk[8];
#pragma unroll
  for (int k = 0; k < 8; ++k) wk[k] = w1[j * 8 + k];
  float bj = b1[j];
  float y[8];
  float s = 0.f, ss = 0.f;
#pragma unroll
  for (int i = 0; i < 8; ++i) {
    int r = tid + i * 256;
    const float4 ga = *(const float4*)&G[r * 8];
    const float4 gb = *(const float4*)&G[r * 8 + 4];
    float acc = bj;
    acc += ga.x * wk[0] + ga.y * wk[1] + ga.z * wk[2] + ga.w * wk[3];
    acc += gb.x * wk[4] + gb.y * wk[5] + gb.z * wk[6] + gb.w * wk[7];
    y[i] = acc;
    s += acc;
    ss += acc * acc;
  }
  __shared__ float red[2][256];
  red[0][tid] = s;
  red[1][tid] = ss;
  __syncthreads();
  for (int off = 128; off > 0; off >>= 1) {
    if (tid < off) {
      red[0][tid] += red[0][tid + off];
      red[1][tid] += red[1][tid + off];
    }
    __syncthreads();
  }
  float mu = red[0][0] * (1.f / 2048.f);
  float var = red[1][0] * (1.f / 2048.f) - mu * mu;
  float scale = g1[j] * rsqrtf(var + EPS);
  float shift = be1[j] - mu * scale;
#pragma unroll
  for (int i = 0; i < 8; ++i) {
    int r = tid + i * 256;
    X1T[j * 2048 + r] = fmaxf(0.f, y[i] * scale + shift);
  }
}

// ---------------- K2: GEMM2  Y2[b][j] = X1[b]·w2[j] + b2[j] ----------------
// A = X1T (k-major: X1T[k*2048+b]), B = w2 row-major (j,k). 64x64 tile, 4x4/thread.
#define BK 16
__global__ __launch_bounds__(256) void k2_gemm2(
    const float* __restrict__ X1T, const float* __restrict__ W2,
    const float* __restrict__ b2, float* __restrict__ Y2) {
  __shared__ float As[BK][64];      // [k][b]
  __shared__ float Bs[BK][64 + 4];  // [k][j], padded
  int b0 = blockIdx.x * 64;
  int j0 = blockIdx.y * 64;
  int tid = threadIdx.x;
  int tx = tid & 15, ty = tid >> 4;
  int a_b = tid & 63, a_k = tid >> 6;   // A load: 64 b x 4 k per pass
  int w_k = tid & 15, w_j = tid >> 4;   // B load: 16 k x 16 j per pass
  float c[4][4] = {};
  for (int k0 = 0; k0 < 1024; k0 += BK) {
#pragma unroll
    for (int p = 0; p < 4; ++p) {
      int kk = a_k + p * 4;
      As[kk][a_b] = X1T[(k0 + kk) * 2048 + b0 + a_b];
    }
#pragma unroll
    for (int p = 0; p < 4; ++p) {
      int jj = w_j + p * 16;
      Bs[w_k][jj] = W2[(j0 + jj) * 1024 + k0 + w_k];
    }
    __syncthreads();
#pragma unroll
    for (int k = 0; k < BK; ++k) {
      float4 a = *(const float4*)&As[k][ty * 4];
      float4 b = *(const float4*)&Bs[k][tx * 4];
      float av[4] = {a.x, a.y, a.z, a.w};
      float bv[4] = {b.x, b.y, b.z, b.w};
#pragma unroll
      for (int i = 0; i < 4; ++i)
#pragma unroll
        for (int jx = 0; jx < 4; ++jx) c[i][jx] += av[i] * bv[jx];
    }
    __syncthreads();
  }
#pragma unroll
  for (int i = 0; i < 4; ++i) {
    int r = b0 + ty * 4 + i;
#pragma unroll
    for (int jx = 0; jx < 4; ++jx) {
      int jj = j0 + tx * 4 + jx;
      Y2[r * 1024 + jj] = c[i][jx] + b2[jj];
    }
  }
}

// ---------------- K3: per-column stats -> scale/shift ----------------
// grid = ncols blocks; scale = g/sqrt(var+eps), shift = be - mu*scale
__global__ __launch_bounds__(256) void k3_stats(
    const float* __restrict__ Y, int ncols, int nrows,
    const float* __restrict__ g, const float* __restrict__ be,
    float* __restrict__ scale, float* __restrict__ shift) {
  int j = blockIdx.x;
  int tid = threadIdx.x;
  float s = 0.f, ss = 0.f;
  for (int r = tid; r < nrows; r += 256) {
    float v = Y[r * ncols + j];
    s += v;
    ss += v * v;
  }
  __shared__ float red[2][256];
  red[0][tid] = s;
  red[1][tid] = ss;
  __syncthreads();
  for (int off = 128; off > 0; off >>= 1) {
    if (tid < off) {
      red[0][tid] += red[0][tid + off];
      red[1][tid] += red[1][tid + off];
    }
    __syncthreads();
  }
  if (tid == 0) {
    float invn = 1.0f / (float)nrows;
    float mu = red[0][0] * invn;
    float var = red[1][0] * invn - mu * mu;
    float sc = g[j] * rsqrtf(var + EPS);
    scale[j] = sc;
    shift[j] = be[j] - mu * sc;
  }
}

// ---------------- K4: GEMM3 with fused BN2+ReLU on A-load ----------------
// Y3[b][j] = relu(bn(Y2[b]))·w3[j] + b3[j],  j < 150
__global__ __launch_bounds__(256) void k4_gemm3(
    const float* __restrict__ Y2, const float* __restrict__ scale2,
    const float* __restrict__ shift2, const float* __restrict__ W3,
    const float* __restrict__ b3, float* __restrict__ Y3) {
  __shared__ float As[BK][64 + 4];
  __shared__ float Bs[BK][64 + 4];
  int b0 = blockIdx.x * 64;
  int j0 = blockIdx.y * 64;
  int tid = threadIdx.x;
  int tx = tid & 15, ty = tid >> 4;
  int l_k = tid & 15, l_r = tid >> 4;  // 16 k x 16 rows per pass
  float c[4][4] = {};
  for (int k0 = 0; k0 < 1024; k0 += BK) {
    float sc = scale2[k0 + l_k], sh = shift2[k0 + l_k];
#pragma unroll
    for (int p = 0; p < 4; ++p) {
      int bb = l_r + p * 16;
      float v = Y2[(b0 + bb) * 1024 + k0 + l_k];
      As[l_k][bb] = fmaxf(0.f, v * sc + sh);
      int jj = l_r + p * 16;
      int j = j0 + jj;
      Bs[l_k][jj] = (j < 150) ? W3[j * 1024 + k0 + l_k] : 0.f;
    }
    __syncthreads();
#pragma unroll
    for (int k = 0; k < BK; ++k) {
      float4 a = *(const float4*)&As[k][ty * 4];
      float4 b = *(const float4*)&Bs[k][tx * 4];
      float av[4] = {a.x, a.y, a.z, a.w};
      float bv[4] = {b.x, b.y, b.z, b.w};
#pragma unroll
      for (int i = 0; i < 4; ++i)
#pragma unroll
        for (int jx = 0; jx < 4; ++jx) c[i][jx] += av[i] * bv[jx];
    }
    __syncthreads();
  }
#pragma unroll
  for (int i = 0; i < 4; ++i) {
    int r = b0 + ty * 4 + i;
#pragma unroll
    for (int jx = 0; jx < 4; ++jx) {
      int jj = j0 + tx * 4 + jx;
      if (jj < 150) Y3[r * 150 + jj] = c[i][jx] + b3[jj];
    }
  }
}

// ---------------- K6: per-row BN3+ReLU + convT chain + lorentz ----------------
// grid = 2048 (one block per batch row), 128 threads.
__global__ __launch_bounds__(128) void k6_conv_lorentz(
    const float* __restrict__ Y3, const float* __restrict__ scale3,
    const float* __restrict__ shift3, const float* __restrict__ ct1_w,
    const float* __restrict__ ct1_b, const float* __restrict__ ct2_w,
    const float* __restrict__ ct2_b, const float* __restrict__ ct3_w,
    const float* __restrict__ ct3_b, const float* __restrict__ cf_w,
    const float* __restrict__ cf_b, float* __restrict__ out) {
  int b = blockIdx.x;
  int tid = threadIdx.x;
  __shared__ float h0[152];
  __shared__ float hA[4][300];
  __shared__ float hB[4][300];
  __shared__ float S[300];
  __shared__ float wt[212];
  // weight table: ct1_w 32 @0 | ct1_b 4 @32 | ct2_w 80 @36 | ct2_b 4 @116 |
  //               ct3_w 80 @120 | ct3_b 4 @200 | cf_w 4 @204 | cf_b 1 @208
  for (int i = tid; i < 209; i += 128) {
    float v;
    if (i < 32) v = ct1_w[i];
    else if (i < 36) v = ct1_b[i - 32];
    else if (i < 116) v = ct2_w[i - 36];
    else if (i < 120) v = ct2_b[i - 116];
    else if (i < 200) v = ct3_w[i - 120];
    else if (i < 204) v = ct3_b[i - 200];
    else if (i < 208) v = cf_w[i - 204];
    else v = cf_b[0];
    wt[i] = v;
  }
  for (int k = tid; k < 150; k += 128)
    h0[k] = fmaxf(0.f, Y3[b * 150 + k] * scale3[k] + shift3[k]);
  __syncthreads();
  // ct1: ci=1, co=4, k=8, stride=2, pad=3 ; 150 -> 300
  for (int t = tid; t < 300; t += 128) {
#pragma unroll
    for (int o = 0; o < 4; ++o) {
      float acc = wt[32 + o];
#pragma unroll
      for (int j = 0; j < 8; ++j) {
        int u = t + 3 - j;
        if (u >= 0 && (u & 1) == 0) {
          int sidx = u >> 1;
          if (sidx < 150) acc += wt[o * 8 + j] * h0[sidx];
        }
      }
      hA[o][t] = acc;
    }
  }
  __syncthreads();
  // ct2: 4->4, k=5, stride=1, pad=2 ; 300 -> 300
  for (int t = tid; t < 300; t += 128) {
#pragma unroll
    for (int o = 0; o < 4; ++o) {
      float acc = wt[116 + o];
#pragma unroll
      for (int i = 0; i < 4; ++i)
#pragma unroll
        for (int j = 0; j < 5; ++j) {
          int u = t + 2 - j;
          if (u >= 0 && u < 300) acc += wt[36 + (i * 4 + o) * 5 + j] * hA[i][u];
        }
      hB[o][t] = acc;
    }
  }
  __syncthreads();
  // ct3 (into hA)
  for (int t = tid; t < 300; t += 128) {
#pragma unroll
    for (int o = 0; o < 4; ++o) {
      float acc = wt[200 + o];
#pragma unroll
      for (int i = 0; i < 4; ++i)
#pragma unroll
        for (int j = 0; j < 5; ++j) {
          int u = t + 2 - j;
          if (u >= 0 && u < 300) acc += wt[120 + (i * 4 + o) * 5 + j] * hB[i][u];
        }
      hA[o][t] = acc;
    }
  }
  __syncthreads();
  // cf 1x1 conv -> S
  for (int t = tid; t < 300; t += 128) {
    float acc = wt[208];
#pragma unroll
    for (int i = 0; i < 4; ++i) acc += wt[204 + i] * hA[i][t];
    S[t] = acc;
  }
  __syncthreads();
  // lorentz
  for (int l = tid; l < 300; l += 128) {
    float wl = 0.8f + (float)l * (1.0f / 300.0f);
    float w2l = wl * wl;
    float acc = 0.f;
    for (int cc = 0; cc < 100; ++cc) {
      float s0 = S[3 * cc], s1 = S[3 * cc + 1], s2 = S[3 * cc + 2];
      float wp2 = s0 * s0;
      float sub1 = s1 * s1 - w2l;
      float denom = sub1 * sub1 + w2l * (s2 * s2);
      float inv = __builtin_amdgcn_rcpf(denom);
      float e1 = wp2 * sub1 * inv;
      float e2 = wp2 * wl * s2 * inv;
      float m = 0.5f * (e1 * e1 + e2 * e2);
      float n = __builtin_amdgcn_sqrtf(fmaxf(m + 0.5f * e1, 0.0f));
      float kap2 = fmaxf(m - 0.5f * e1, 0.0f);
      float den2 = (n + 1.0f) * (n + 1.0f) + kap2;
      acc += 4.0f * n * __builtin_amdgcn_rcpf(den2);
    }
    out[b * 300 + l] = acc;
  }
}

extern "C" void kernel_launch(void* const* d_in, const int* in_sizes, int n_in,
                              void* d_out, int out_size, void* d_ws,
                              size_t ws_size, hipStream_t stream) {
  const float* G = (const float*)d_in[0];
  const float* w1 = (const float*)d_in[1];
  const float* b1 = (const float*)d_in[2];
  const float* g1 = (const float*)d_in[3];
  const float* be1 = (const float*)d_in[4];
  const float* w2 = (const float*)d_in[5];
  const float* b2 = (const float*)d_in[6];
  const float* g2 = (const float*)d_in[7];
  const float* be2 = (const float*)d_in[8];
  const float* w3 = (const float*)d_in[9];
  const float* b3 = (const float*)d_in[10];
  const float* g3 = (const float*)d_in[11];
  const float* be3 = (const float*)d_in[12];
  const float* ct1_w = (const float*)d_in[13];
  const float* ct1_b = (const float*)d_in[14];
  const float* ct2_w = (const float*)d_in[15];
  const float* ct2_b = (const float*)d_in[16];
  const float* ct3_w = (const float*)d_in[17];
  const float* ct3_b = (const float*)d_in[18];
  const float* cf_w = (const float*)d_in[19];
  const float* cf_b = (const float*)d_in[20];
  float* out = (float*)d_out;

  float* ws = (float*)d_ws;
  float* X1T = ws;                       // 1024*2048 = 2,097,152 floats
  float* Y2 = ws + 2097152;              // 2048*1024 = 2,097,152 floats
  float* Y3 = ws;                        // reuse X1T region (2048*150)
  float* scale2 = ws + 4194304;          // 1024
  float* shift2 = scale2 + 1024;         // 1024
  float* scale3 = shift2 + 1024;         // 150
  float* shift3 = scale3 + 150;          // 150

  k1_layer1<<<1024, 256, 0, stream>>>(G, w1, b1, g1, be1, X1T);
  k2_gemm2<<<dim3(32, 16), 256, 0, stream>>>(X1T, w2, b2, Y2);
  k3_stats<<<1024, 256, 0, stream>>>(Y2, 1024, 2048, g2, be2, scale2, shift2);
  k4_gemm3<<<dim3(32, 3), 256, 0, stream>>>(Y2, scale2, shift2, w3, b3, Y3);
  k3_stats<<<150, 256, 0, stream>>>(Y3, 150, 2048, g3, be3, scale3, shift3);
  k6_conv_lorentz<<<2048, 128, 0, stream>>>(Y3, scale3, shift3, ct1_w, ct1_b,
                                            ct2_w, ct2_b, ct3_w, ct3_b, cf_w,
                                            cf_b, out);
}

// Round 2
// 186.353 us; speedup vs baseline: 1.5105x; 1.5105x over previous
//
#include <hip/hip_runtime.h>
#include <hip/hip_bf16.h>

#define EPS 1e-5f

typedef __attribute__((ext_vector_type(8))) short bf16x8;
typedef __attribute__((ext_vector_type(4))) float f32x4;

__device__ __forceinline__ ushort f2bf(float x) {
  __hip_bfloat16 h = __float2bfloat16(x);
  return *reinterpret_cast<ushort*>(&h);
}
__device__ __forceinline__ float bf2f(ushort u) {
  __hip_bfloat16 h;
  *reinterpret_cast<ushort*>(&h) = u;
  return __bfloat162float(h);
}

// ---------------- k1s: layer1 stats (recompute Y1 on the fly) ----------------
// grid 64 (32 rows each), 256 threads (4 cols each). Partials -> psum/psqs.
__global__ __launch_bounds__(256) void k1s(const float* __restrict__ G,
                                           const float* __restrict__ W1,
                                           const float* __restrict__ b1,
                                           float* __restrict__ psum,
                                           float* __restrict__ psqs) {
  int r0 = blockIdx.x * 32;
  int c = threadIdx.x * 4;
  float w[4][8];
#pragma unroll
  for (int q = 0; q < 4; ++q)
#pragma unroll
    for (int k = 0; k < 8; ++k) w[q][k] = W1[(c + q) * 8 + k];
  float b4[4];
#pragma unroll
  for (int q = 0; q < 4; ++q) b4[q] = b1[c + q];
  float s[4] = {}, ss[4] = {};
  for (int r = 0; r < 32; ++r) {
    const float4 g0 = *(const float4*)&G[(size_t)(r0 + r) * 8];
    const float4 g1 = *(const float4*)&G[(size_t)(r0 + r) * 8 + 4];
    float gr[8] = {g0.x, g0.y, g0.z, g0.w, g1.x, g1.y, g1.z, g1.w};
#pragma unroll
    for (int q = 0; q < 4; ++q) {
      float acc = b4[q];
#pragma unroll
      for (int k = 0; k < 8; ++k) acc += gr[k] * w[q][k];
      s[q] += acc;
      ss[q] += acc * acc;
    }
  }
#pragma unroll
  for (int q = 0; q < 4; ++q) {
    psum[blockIdx.x * 1024 + c + q] = s[q];
    psqs[blockIdx.x * 1024 + c + q] = ss[q];
  }
}

// ---------------- k3b: finalize column stats -> scale/shift ----------------
// grid: ncols/256 blocks. 64 partials, stride 1024.
__global__ __launch_bounds__(256) void k3b(const float* __restrict__ psum,
                                           const float* __restrict__ psqs,
                                           const float* __restrict__ g,
                                           const float* __restrict__ be,
                                           float* __restrict__ scale,
                                           float* __restrict__ shift) {
  int j = blockIdx.x * 256 + threadIdx.x;
  float s = 0.f, ss = 0.f;
  for (int p = 0; p < 64; ++p) {
    s += psum[p * 1024 + j];
    ss += psqs[p * 1024 + j];
  }
  float mu = s * (1.f / 2048.f);
  float var = ss * (1.f / 2048.f) - mu * mu;
  float sc = g[j] * rsqrtf(var + EPS);
  scale[j] = sc;
  shift[j] = be[j] - mu * sc;
}

// ---------------- k1c: recompute Y1, BN+ReLU, split to bf16 hi/lo ----------------
__global__ __launch_bounds__(256) void k1c(
    const float* __restrict__ G, const float* __restrict__ W1,
    const float* __restrict__ b1, const float* __restrict__ scale1,
    const float* __restrict__ shift1, ushort* __restrict__ X1hi,
    ushort* __restrict__ X1lo) {
  int r0 = blockIdx.x * 32;
  int c = threadIdx.x * 4;
  float w[4][8];
#pragma unroll
  for (int q = 0; q < 4; ++q)
#pragma unroll
    for (int k = 0; k < 8; ++k) w[q][k] = W1[(c + q) * 8 + k];
  float b4[4], sc[4], sh[4];
#pragma unroll
  for (int q = 0; q < 4; ++q) {
    b4[q] = b1[c + q];
    sc[q] = scale1[c + q];
    sh[q] = shift1[c + q];
  }
  for (int r = 0; r < 32; ++r) {
    const float4 g0 = *(const float4*)&G[(size_t)(r0 + r) * 8];
    const float4 g1 = *(const float4*)&G[(size_t)(r0 + r) * 8 + 4];
    float gr[8] = {g0.x, g0.y, g0.z, g0.w, g1.x, g1.y, g1.z, g1.w};
    ushort hs[4], ls[4];
#pragma unroll
    for (int q = 0; q < 4; ++q) {
      float acc = b4[q];
#pragma unroll
      for (int k = 0; k < 8; ++k) acc += gr[k] * w[q][k];
      float x = fmaxf(0.f, acc * sc[q] + sh[q]);
      ushort h = f2bf(x);
      float hf = bf2f(h);
      hs[q] = h;
      ls[q] = f2bf(x - hf);
    }
    size_t o = (size_t)(r0 + r) * 1024 + c;
    *(ushort4*)&X1hi[o] = make_ushort4(hs[0], hs[1], hs[2], hs[3]);
    *(ushort4*)&X1lo[o] = make_ushort4(ls[0], ls[1], ls[2], ls[3]);
  }
}

// ---------------- k2: MFMA bf16 hi/lo GEMM2 ----------------
// C[2048x1024] = X1 @ W2^T + b2.  Tile 128(M) x 64(N) x 64(K), 4 waves.
// A: X1hi/lo bf16 [b][k]; B: W2 fp32 [j][k] converted on the fly.
// LDS XOR-swizzle: 16B chunk c at row r stored at slot c^(r&7).
__global__ __launch_bounds__(256) void k2_mfma(
    const ushort* __restrict__ X1hi, const ushort* __restrict__ X1lo,
    const float* __restrict__ W2, const float* __restrict__ b2,
    float* __restrict__ Y2) {
  __shared__ short lAhi[128 * 64], lAlo[128 * 64];
  __shared__ short lBhi[64 * 64], lBlo[64 * 64];
  // XCD-aware swizzle: each XCD gets a 4x4 (bx) x (by) region
  int id = blockIdx.x;
  int xcd = id & 7, slot = id >> 3;
  int g = slot >> 4, wi = slot & 15;
  int bx = (xcd & 3) * 4 + (wi & 3);
  int by = ((xcd >> 2) * 2 + g) * 4 + (wi >> 2);
  int b0 = bx * 128, j0 = by * 64;
  int tid = threadIdx.x;
  int lane = tid & 63, wave = tid >> 6;
  int wm = wave >> 1, wn = wave & 1;
  int brow = tid >> 2, bkq = tid & 3;
  f32x4 acc[4][2] = {};
  for (int k0 = 0; k0 < 1024; k0 += 64) {
    // --- stage A (hi+lo): thread handles 4 chunks, linear global, swizzled LDS dest
#pragma unroll
    for (int i = 0; i < 4; ++i) {
      int chunk = tid * 4 + i;  // 0..1023
      int row = chunk >> 3, c = chunk & 7;
      size_t go = (size_t)(b0 + row) * 1024 + k0 + c * 8;
      bf16x8 vh = *(const bf16x8*)&X1hi[go];
      bf16x8 vl = *(const bf16x8*)&X1lo[go];
      int d = row * 64 + ((c ^ (row & 7)) << 3);
      *(bf16x8*)&lAhi[d] = vh;
      *(bf16x8*)&lAlo[d] = vl;
    }
    // --- stage B: fp32 load + hi/lo convert + swizzled ds_write
    {
      const float* src = &W2[(size_t)(j0 + brow) * 1024 + k0 + bkq * 16];
      float4 f0 = *(const float4*)(src);
      float4 f1 = *(const float4*)(src + 4);
      float4 f2 = *(const float4*)(src + 8);
      float4 f3 = *(const float4*)(src + 12);
      float v[16] = {f0.x, f0.y, f0.z, f0.w, f1.x, f1.y, f1.z, f1.w,
                     f2.x, f2.y, f2.z, f2.w, f3.x, f3.y, f3.z, f3.w};
      bf16x8 h0, l0, h1, l1;
#pragma unroll
      for (int e = 0; e < 8; ++e) {
        ushort h = f2bf(v[e]);
        h0[e] = (short)h;
        l0[e] = (short)f2bf(v[e] - bf2f(h));
      }
#pragma unroll
      for (int e = 0; e < 8; ++e) {
        ushort h = f2bf(v[8 + e]);
        h1[e] = (short)h;
        l1[e] = (short)f2bf(v[8 + e] - bf2f(h));
      }
      int c0 = bkq * 2, c1 = bkq * 2 + 1;
      int d0 = brow * 64 + ((c0 ^ (brow & 7)) << 3);
      int d1 = brow * 64 + ((c1 ^ (brow & 7)) << 3);
      *(bf16x8*)&lBhi[d0] = h0;
      *(bf16x8*)&lBlo[d0] = l0;
      *(bf16x8*)&lBhi[d1] = h1;
      *(bf16x8*)&lBlo[d1] = l1;
    }
    __syncthreads();
#pragma unroll
    for (int kk = 0; kk < 2; ++kk) {
      bf16x8 ah[4], al[4], bh[2], bl[2];
#pragma unroll
      for (int mi = 0; mi < 4; ++mi) {
        int r = wm * 64 + mi * 16 + (lane & 15);
        int cc = (((kk << 2) + (lane >> 4)) ^ (r & 7)) << 3;
        ah[mi] = *(const bf16x8*)&lAhi[r * 64 + cc];
        al[mi] = *(const bf16x8*)&lAlo[r * 64 + cc];
      }
#pragma unroll
      for (int ni = 0; ni < 2; ++ni) {
        int r = wn * 32 + ni * 16 + (lane & 15);
        int cc = (((kk << 2) + (lane >> 4)) ^ (r & 7)) << 3;
        bh[ni] = *(const bf16x8*)&lBhi[r * 64 + cc];
        bl[ni] = *(const bf16x8*)&lBlo[r * 64 + cc];
      }
#pragma unroll
      for (int mi = 0; mi < 4; ++mi)
#pragma unroll
        for (int ni = 0; ni < 2; ++ni) {
          acc[mi][ni] = __builtin_amdgcn_mfma_f32_16x16x32_bf16(
              ah[mi], bh[ni], acc[mi][ni], 0, 0, 0);
          acc[mi][ni] = __builtin_amdgcn_mfma_f32_16x16x32_bf16(
              al[mi], bh[ni], acc[mi][ni], 0, 0, 0);
          acc[mi][ni] = __builtin_amdgcn_mfma_f32_16x16x32_bf16(
              ah[mi], bl[ni], acc[mi][ni], 0, 0, 0);
        }
    }
    __syncthreads();
  }
  // epilogue: C/D layout col=lane&15, row=(lane>>4)*4+reg
  float bb[2];
#pragma unroll
  for (int ni = 0; ni < 2; ++ni) bb[ni] = b2[j0 + wn * 32 + ni * 16 + (lane & 15)];
#pragma unroll
  for (int mi = 0; mi < 4; ++mi)
#pragma unroll
    for (int ni = 0; ni < 2; ++ni) {
      int col = j0 + wn * 32 + ni * 16 + (lane & 15);
#pragma unroll
      for (int r = 0; r < 4; ++r) {
        int row = b0 + wm * 64 + mi * 16 + (lane >> 4) * 4 + r;
        Y2[(size_t)row * 1024 + col] = acc[mi][ni][r] + bb[ni];
      }
    }
}

// ---------------- k3a: partial column stats over Y (2048 x 1024) ----------------
__global__ __launch_bounds__(256) void k3a(const float* __restrict__ Y,
                                           float* __restrict__ psum,
                                           float* __restrict__ psqs) {
  int r0 = blockIdx.x * 32;
  int c = threadIdx.x * 4;
  float s[4] = {}, ss[4] = {};
  for (int r = 0; r < 32; ++r) {
    float4 v = *(const float4*)&Y[(size_t)(r0 + r) * 1024 + c];
    float e[4] = {v.x, v.y, v.z, v.w};
#pragma unroll
    for (int q = 0; q < 4; ++q) {
      s[q] += e[q];
      ss[q] += e[q] * e[q];
    }
  }
#pragma unroll
  for (int q = 0; q < 4; ++q) {
    psum[blockIdx.x * 1024 + c + q] = s[q];
    psqs[blockIdx.x * 1024 + c + q] = ss[q];
  }
}

// ---------------- k4: GEMM3 split-K, fused BN2+ReLU on A ----------------
// grid (32, 3, 4): 64x64 tile, K-slice 256. Partials P[kz][2048][150].
__global__ __launch_bounds__(256) void k4_gemm3(
    const float* __restrict__ Y2, const float* __restrict__ scale2,
    const float* __restrict__ shift2, const float* __restrict__ W3,
    float* __restrict__ P) {
  __shared__ float As[64][17], Bs[64][17];
  int b0 = blockIdx.x * 64, j0 = blockIdx.y * 64, kz = blockIdx.z;
  int tid = threadIdx.x;
  int tx = tid & 15, ty = tid >> 4;
  int lrow = tid >> 2, lkq = (tid & 3) * 4;
  float c[4][4] = {};
  int kbase = kz * 256;
  for (int k0 = kbase; k0 < kbase + 256; k0 += 16) {
    float4 sc = *(const float4*)&scale2[k0 + lkq];
    float4 sh = *(const float4*)&shift2[k0 + lkq];
    float4 av = *(const float4*)&Y2[(size_t)(b0 + lrow) * 1024 + k0 + lkq];
    As[lrow][lkq + 0] = fmaxf(0.f, av.x * sc.x + sh.x);
    As[lrow][lkq + 1] = fmaxf(0.f, av.y * sc.y + sh.y);
    As[lrow][lkq + 2] = fmaxf(0.f, av.z * sc.z + sh.z);
    As[lrow][lkq + 3] = fmaxf(0.f, av.w * sc.w + sh.w);
    int j = j0 + lrow;
    float4 bv = make_float4(0.f, 0.f, 0.f, 0.f);
    if (j < 150) bv = *(const float4*)&W3[(size_t)j * 1024 + k0 + lkq];
    Bs[lrow][lkq + 0] = bv.x;
    Bs[lrow][lkq + 1] = bv.y;
    Bs[lrow][lkq + 2] = bv.z;
    Bs[lrow][lkq + 3] = bv.w;
    __syncthreads();
#pragma unroll
    for (int k = 0; k < 16; ++k) {
      float a[4], b[4];
#pragma unroll
      for (int i = 0; i < 4; ++i) a[i] = As[ty * 4 + i][k];
#pragma unroll
      for (int jx = 0; jx < 4; ++jx) b[jx] = Bs[tx * 4 + jx][k];
#pragma unroll
      for (int i = 0; i < 4; ++i)
#pragma unroll
        for (int jx = 0; jx < 4; ++jx) c[i][jx] += a[i] * b[jx];
    }
    __syncthreads();
  }
#pragma unroll
  for (int i = 0; i < 4; ++i) {
    int r = b0 + ty * 4 + i;
#pragma unroll
    for (int jx = 0; jx < 4; ++jx) {
      int jj = j0 + tx * 4 + jx;
      if (jj < 150) P[((size_t)kz * 2048 + r) * 150 + jj] = c[i][jx];
    }
  }
}

// ---------------- k5a: reduce split-K partials + b3 -> Y3, partial stats ----------------
__global__ __launch_bounds__(256) void k5a(const float* __restrict__ P,
                                           const float* __restrict__ b3,
                                           float* __restrict__ Y3,
                                           float* __restrict__ psum,
                                           float* __restrict__ psqs) {
  int r0 = blockIdx.x * 32;
  int j = threadIdx.x;
  if (j >= 150) return;
  float bj = b3[j];
  float s = 0.f, ss = 0.f;
  for (int r = 0; r < 32; ++r) {
    size_t base = (size_t)(r0 + r) * 150 + j;
    float v = bj + P[base] + P[base + 2048 * 150] + P[base + 2 * 2048 * 150] +
              P[base + 3 * 2048 * 150];
    Y3[(size_t)(r0 + r) * 150 + j] = v;
    s += v;
    ss += v * v;
  }
  psum[blockIdx.x * 160 + j] = s;
  psqs[blockIdx.x * 160 + j] = ss;
}

__global__ __launch_bounds__(256) void k5b(const float* __restrict__ psum,
                                           const float* __restrict__ psqs,
                                           const float* __restrict__ g3,
                                           const float* __restrict__ be3,
                                           float* __restrict__ scale3,
                                           float* __restrict__ shift3) {
  int j = threadIdx.x;
  if (j >= 150) return;
  float s = 0.f, ss = 0.f;
  for (int p = 0; p < 64; ++p) {
    s += psum[p * 160 + j];
    ss += psqs[p * 160 + j];
  }
  float mu = s * (1.f / 2048.f);
  float var = ss * (1.f / 2048.f) - mu * mu;
  float sc = g3[j] * rsqrtf(var + EPS);
  scale3[j] = sc;
  shift3[j] = be3[j] - mu * sc;
}

// ---------------- k6: per-row BN3+ReLU + convT chain + lorentz ----------------
__global__ __launch_bounds__(128) void k6_conv_lorentz(
    const float* __restrict__ Y3, const float* __restrict__ scale3,
    const float* __restrict__ shift3, const float* __restrict__ ct1_w,
    const float* __restrict__ ct1_b, const float* __restrict__ ct2_w,
    const float* __restrict__ ct2_b, const float* __restrict__ ct3_w,
    const float* __restrict__ ct3_b, const float* __restrict__ cf_w,
    const float* __restrict__ cf_b, float* __restrict__ out) {
  int b = blockIdx.x;
  int tid = threadIdx.x;
  __shared__ float h0[152];
  __shared__ float hA[4][300];
  __shared__ float hB[4][300];
  __shared__ float S[300];
  __shared__ float wt[212];
  for (int i = tid; i < 209; i += 128) {
    float v;
    if (i < 32) v = ct1_w[i];
    else if (i < 36) v = ct1_b[i - 32];
    else if (i < 116) v = ct2_w[i - 36];
    else if (i < 120) v = ct2_b[i - 116];
    else if (i < 200) v = ct3_w[i - 120];
    else if (i < 204) v = ct3_b[i - 200];
    else if (i < 208) v = cf_w[i - 204];
    else v = cf_b[0];
    wt[i] = v;
  }
  for (int k = tid; k < 150; k += 128)
    h0[k] = fmaxf(0.f, Y3[(size_t)b * 150 + k] * scale3[k] + shift3[k]);
  __syncthreads();
  for (int t = tid; t < 300; t += 128) {
#pragma unroll
    for (int o = 0; o < 4; ++o) {
      float acc = wt[32 + o];
#pragma unroll
      for (int j = 0; j < 8; ++j) {
        int u = t + 3 - j;
        if (u >= 0 && (u & 1) == 0) {
          int sidx = u >> 1;
          if (sidx < 150) acc += wt[o * 8 + j] * h0[sidx];
        }
      }
      hA[o][t] = acc;
    }
  }
  __syncthreads();
  for (int t = tid; t < 300; t += 128) {
#pragma unroll
    for (int o = 0; o < 4; ++o) {
      float acc = wt[116 + o];
#pragma unroll
      for (int i = 0; i < 4; ++i)
#pragma unroll
        for (int j = 0; j < 5; ++j) {
          int u = t + 2 - j;
          if (u >= 0 && u < 300) acc += wt[36 + (i * 4 + o) * 5 + j] * hA[i][u];
        }
      hB[o][t] = acc;
    }
  }
  __syncthreads();
  for (int t = tid; t < 300; t += 128) {
#pragma unroll
    for (int o = 0; o < 4; ++o) {
      float acc = wt[200 + o];
#pragma unroll
      for (int i = 0; i < 4; ++i)
#pragma unroll
        for (int j = 0; j < 5; ++j) {
          int u = t + 2 - j;
          if (u >= 0 && u < 300) acc += wt[120 + (i * 4 + o) * 5 + j] * hB[i][u];
        }
      hA[o][t] = acc;
    }
  }
  __syncthreads();
  for (int t = tid; t < 300; t += 128) {
    float acc = wt[208];
#pragma unroll
    for (int i = 0; i < 4; ++i) acc += wt[204 + i] * hA[i][t];
    S[t] = acc;
  }
  __syncthreads();
  for (int l = tid; l < 300; l += 128) {
    float wl = 0.8f + (float)l * (1.0f / 300.0f);
    float w2l = wl * wl;
    float acc = 0.f;
    for (int cc = 0; cc < 100; ++cc) {
      float s0 = S[3 * cc], s1 = S[3 * cc + 1], s2 = S[3 * cc + 2];
      float wp2 = s0 * s0;
      float sub1 = s1 * s1 - w2l;
      float denom = sub1 * sub1 + w2l * (s2 * s2);
      float inv = __builtin_amdgcn_rcpf(denom);
      float e1 = wp2 * sub1 * inv;
      float e2 = wp2 * wl * s2 * inv;
      float m = 0.5f * (e1 * e1 + e2 * e2);
      float n = __builtin_amdgcn_sqrtf(fmaxf(m + 0.5f * e1, 0.0f));
      float kap2 = fmaxf(m - 0.5f * e1, 0.0f);
      float den2 = (n + 1.0f) * (n + 1.0f) + kap2;
      acc += 4.0f * n * __builtin_amdgcn_rcpf(den2);
    }
    out[(size_t)b * 300 + l] = acc;
  }
}

extern "C" void kernel_launch(void* const* d_in, const int* in_sizes, int n_in,
                              void* d_out, int out_size, void* d_ws,
                              size_t ws_size, hipStream_t stream) {
  const float* G = (const float*)d_in[0];
  const float* w1 = (const float*)d_in[1];
  const float* b1 = (const float*)d_in[2];
  const float* g1 = (const float*)d_in[3];
  const float* be1 = (const float*)d_in[4];
  const float* w2 = (const float*)d_in[5];
  const float* b2 = (const float*)d_in[6];
  const float* g2 = (const float*)d_in[7];
  const float* be2 = (const float*)d_in[8];
  const float* w3 = (const float*)d_in[9];
  const float* b3 = (const float*)d_in[10];
  const float* g3 = (const float*)d_in[11];
  const float* be3 = (const float*)d_in[12];
  const float* ct1_w = (const float*)d_in[13];
  const float* ct1_b = (const float*)d_in[14];
  const float* ct2_w = (const float*)d_in[15];
  const float* ct2_b = (const float*)d_in[16];
  const float* ct3_w = (const float*)d_in[17];
  const float* ct3_b = (const float*)d_in[18];
  const float* cf_w = (const float*)d_in[19];
  const float* cf_b = (const float*)d_in[20];
  float* out = (float*)d_out;

  float* ws = (float*)d_ws;
  // layout (float offsets):
  float* Y2 = ws;                              // [0, 2097152)
  ushort* X1hi = (ushort*)(ws + 2097152);      // 2M ushorts = 1,048,576 fs
  ushort* X1lo = (ushort*)(ws + 3145728);      // 2M ushorts
  float* P = ws + 2097152;                     // after k2 (X1 dead): 1,228,800
  float* Y3 = ws + 3325952;                    // 307,200
  float* psum = ws + 3633152;                  // 65,536
  float* psqs = ws + 3698688;                  // 65,536
  float* scale1 = ws + 4194304;                // scales block (outside X1 region)
  float* shift1 = scale1 + 1024;
  float* scale2 = scale1 + 2048;
  float* shift2 = scale1 + 3072;
  float* scale3 = scale1 + 4096;
  float* shift3 = scale1 + 4256;

  k1s<<<64, 256, 0, stream>>>(G, w1, b1, psum, psqs);
  k3b<<<4, 256, 0, stream>>>(psum, psqs, g1, be1, scale1, shift1);
  k1c<<<64, 256, 0, stream>>>(G, w1, b1, scale1, shift1, X1hi, X1lo);
  k2_mfma<<<256, 256, 0, stream>>>(X1hi, X1lo, w2, b2, Y2);
  k3a<<<64, 256, 0, stream>>>(Y2, psum, psqs);
  k3b<<<4, 256, 0, stream>>>(psum, psqs, g2, be2, scale2, shift2);
  k4_gemm3<<<dim3(32, 3, 4), 256, 0, stream>>>(Y2, scale2, shift2, w3, P);
  k5a<<<64, 256, 0, stream>>>(P, b3, Y3, psum, psqs);
  k5b<<<1, 256, 0, stream>>>(psum, psqs, g3, be3, scale3, shift3);
  k6_conv_lorentz<<<2048, 128, 0, stream>>>(Y3, scale3, shift3, ct1_w, ct1_b,
                                            ct2_w, ct2_b, ct3_w, ct3_b, cf_w,
                                            cf_b, out);
}

// Round 3
// 162.124 us; speedup vs baseline: 1.7363x; 1.1494x over previous
//
#include <hip/hip_runtime.h>
#include <hip/hip_bf16.h>

#define EPS 1e-5f

typedef __attribute__((ext_vector_type(8))) short bf16x8;
typedef __attribute__((ext_vector_type(4))) float f32x4;

__device__ __forceinline__ ushort f2bf(float x) {
  __hip_bfloat16 h = __float2bfloat16(x);
  return *reinterpret_cast<ushort*>(&h);
}
__device__ __forceinline__ float bf2f(ushort u) {
  __hip_bfloat16 h;
  *reinterpret_cast<ushort*>(&h) = u;
  return __bfloat162float(h);
}

// ---------------- k1s: layer1 stats (recompute Y1 on the fly) ----------------
__global__ __launch_bounds__(256) void k1s(const float* __restrict__ G,
                                           const float* __restrict__ W1,
                                           const float* __restrict__ b1,
                                           float* __restrict__ psum,
                                           float* __restrict__ psqs) {
  int r0 = blockIdx.x * 32;
  int c = threadIdx.x * 4;
  float w[4][8];
#pragma unroll
  for (int q = 0; q < 4; ++q)
#pragma unroll
    for (int k = 0; k < 8; ++k) w[q][k] = W1[(c + q) * 8 + k];
  float b4[4];
#pragma unroll
  for (int q = 0; q < 4; ++q) b4[q] = b1[c + q];
  float s[4] = {}, ss[4] = {};
  for (int r = 0; r < 32; ++r) {
    const float4 g0 = *(const float4*)&G[(size_t)(r0 + r) * 8];
    const float4 g1 = *(const float4*)&G[(size_t)(r0 + r) * 8 + 4];
    float gr[8] = {g0.x, g0.y, g0.z, g0.w, g1.x, g1.y, g1.z, g1.w};
#pragma unroll
    for (int q = 0; q < 4; ++q) {
      float acc = b4[q];
#pragma unroll
      for (int k = 0; k < 8; ++k) acc += gr[k] * w[q][k];
      s[q] += acc;
      ss[q] += acc * acc;
    }
  }
#pragma unroll
  for (int q = 0; q < 4; ++q) {
    psum[blockIdx.x * 1024 + c + q] = s[q];
    psqs[blockIdx.x * 1024 + c + q] = ss[q];
  }
}

// ---------------- k3b: finalize column stats -> scale/shift ----------------
__global__ __launch_bounds__(256) void k3b(const float* __restrict__ psum,
                                           const float* __restrict__ psqs,
                                           const float* __restrict__ g,
                                           const float* __restrict__ be,
                                           float* __restrict__ scale,
                                           float* __restrict__ shift) {
  int j = blockIdx.x * 256 + threadIdx.x;
  float s = 0.f, ss = 0.f;
  for (int p = 0; p < 64; ++p) {
    s += psum[p * 1024 + j];
    ss += psqs[p * 1024 + j];
  }
  float mu = s * (1.f / 2048.f);
  float var = ss * (1.f / 2048.f) - mu * mu;
  float sc = g[j] * rsqrtf(var + EPS);
  scale[j] = sc;
  shift[j] = be[j] - mu * sc;
}

// ---------------- k1c: recompute Y1, BN+ReLU, split to bf16 hi/lo ----------------
__global__ __launch_bounds__(256) void k1c(
    const float* __restrict__ G, const float* __restrict__ W1,
    const float* __restrict__ b1, const float* __restrict__ scale1,
    const float* __restrict__ shift1, ushort* __restrict__ X1hi,
    ushort* __restrict__ X1lo) {
  int r0 = blockIdx.x * 32;
  int c = threadIdx.x * 4;
  float w[4][8];
#pragma unroll
  for (int q = 0; q < 4; ++q)
#pragma unroll
    for (int k = 0; k < 8; ++k) w[q][k] = W1[(c + q) * 8 + k];
  float b4[4], sc[4], sh[4];
#pragma unroll
  for (int q = 0; q < 4; ++q) {
    b4[q] = b1[c + q];
    sc[q] = scale1[c + q];
    sh[q] = shift1[c + q];
  }
  for (int r = 0; r < 32; ++r) {
    const float4 g0 = *(const float4*)&G[(size_t)(r0 + r) * 8];
    const float4 g1 = *(const float4*)&G[(size_t)(r0 + r) * 8 + 4];
    float gr[8] = {g0.x, g0.y, g0.z, g0.w, g1.x, g1.y, g1.z, g1.w};
    ushort hs[4], ls[4];
#pragma unroll
    for (int q = 0; q < 4; ++q) {
      float acc = b4[q];
#pragma unroll
      for (int k = 0; k < 8; ++k) acc += gr[k] * w[q][k];
      float x = fmaxf(0.f, acc * sc[q] + sh[q]);
      ushort h = f2bf(x);
      float hf = bf2f(h);
      hs[q] = h;
      ls[q] = f2bf(x - hf);
    }
    size_t o = (size_t)(r0 + r) * 1024 + c;
    *(ushort4*)&X1hi[o] = make_ushort4(hs[0], hs[1], hs[2], hs[3]);
    *(ushort4*)&X1lo[o] = make_ushort4(ls[0], ls[1], ls[2], ls[3]);
  }
}

// ---------------- k2: MFMA bf16 hi/lo GEMM2 ----------------
__global__ __launch_bounds__(256) void k2_mfma(
    const ushort* __restrict__ X1hi, const ushort* __restrict__ X1lo,
    const float* __restrict__ W2, const float* __restrict__ b2,
    float* __restrict__ Y2) {
  __shared__ short lAhi[128 * 64], lAlo[128 * 64];
  __shared__ short lBhi[64 * 64], lBlo[64 * 64];
  int id = blockIdx.x;
  int xcd = id & 7, slot = id >> 3;
  int g = slot >> 4, wi = slot & 15;
  int bx = (xcd & 3) * 4 + (wi & 3);
  int by = ((xcd >> 2) * 2 + g) * 4 + (wi >> 2);
  int b0 = bx * 128, j0 = by * 64;
  int tid = threadIdx.x;
  int lane = tid & 63, wave = tid >> 6;
  int wm = wave >> 1, wn = wave & 1;
  int brow = tid >> 2, bkq = tid & 3;
  f32x4 acc[4][2] = {};
  for (int k0 = 0; k0 < 1024; k0 += 64) {
#pragma unroll
    for (int i = 0; i < 4; ++i) {
      int chunk = tid * 4 + i;
      int row = chunk >> 3, c = chunk & 7;
      size_t go = (size_t)(b0 + row) * 1024 + k0 + c * 8;
      bf16x8 vh = *(const bf16x8*)&X1hi[go];
      bf16x8 vl = *(const bf16x8*)&X1lo[go];
      int d = row * 64 + ((c ^ (row & 7)) << 3);
      *(bf16x8*)&lAhi[d] = vh;
      *(bf16x8*)&lAlo[d] = vl;
    }
    {
      const float* src = &W2[(size_t)(j0 + brow) * 1024 + k0 + bkq * 16];
      float4 f0 = *(const float4*)(src);
      float4 f1 = *(const float4*)(src + 4);
      float4 f2 = *(const float4*)(src + 8);
      float4 f3 = *(const float4*)(src + 12);
      float v[16] = {f0.x, f0.y, f0.z, f0.w, f1.x, f1.y, f1.z, f1.w,
                     f2.x, f2.y, f2.z, f2.w, f3.x, f3.y, f3.z, f3.w};
      bf16x8 h0, l0, h1, l1;
#pragma unroll
      for (int e = 0; e < 8; ++e) {
        ushort h = f2bf(v[e]);
        h0[e] = (short)h;
        l0[e] = (short)f2bf(v[e] - bf2f(h));
      }
#pragma unroll
      for (int e = 0; e < 8; ++e) {
        ushort h = f2bf(v[8 + e]);
        h1[e] = (short)h;
        l1[e] = (short)f2bf(v[8 + e] - bf2f(h));
      }
      int c0 = bkq * 2, c1 = bkq * 2 + 1;
      int d0 = brow * 64 + ((c0 ^ (brow & 7)) << 3);
      int d1 = brow * 64 + ((c1 ^ (brow & 7)) << 3);
      *(bf16x8*)&lBhi[d0] = h0;
      *(bf16x8*)&lBlo[d0] = l0;
      *(bf16x8*)&lBhi[d1] = h1;
      *(bf16x8*)&lBlo[d1] = l1;
    }
    __syncthreads();
#pragma unroll
    for (int kk = 0; kk < 2; ++kk) {
      bf16x8 ah[4], al[4], bh[2], bl[2];
#pragma unroll
      for (int mi = 0; mi < 4; ++mi) {
        int r = wm * 64 + mi * 16 + (lane & 15);
        int cc = (((kk << 2) + (lane >> 4)) ^ (r & 7)) << 3;
        ah[mi] = *(const bf16x8*)&lAhi[r * 64 + cc];
        al[mi] = *(const bf16x8*)&lAlo[r * 64 + cc];
      }
#pragma unroll
      for (int ni = 0; ni < 2; ++ni) {
        int r = wn * 32 + ni * 16 + (lane & 15);
        int cc = (((kk << 2) + (lane >> 4)) ^ (r & 7)) << 3;
        bh[ni] = *(const bf16x8*)&lBhi[r * 64 + cc];
        bl[ni] = *(const bf16x8*)&lBlo[r * 64 + cc];
      }
#pragma unroll
      for (int mi = 0; mi < 4; ++mi)
#pragma unroll
        for (int ni = 0; ni < 2; ++ni) {
          acc[mi][ni] = __builtin_amdgcn_mfma_f32_16x16x32_bf16(
              ah[mi], bh[ni], acc[mi][ni], 0, 0, 0);
          acc[mi][ni] = __builtin_amdgcn_mfma_f32_16x16x32_bf16(
              al[mi], bh[ni], acc[mi][ni], 0, 0, 0);
          acc[mi][ni] = __builtin_amdgcn_mfma_f32_16x16x32_bf16(
              ah[mi], bl[ni], acc[mi][ni], 0, 0, 0);
        }
    }
    __syncthreads();
  }
  float bb[2];
#pragma unroll
  for (int ni = 0; ni < 2; ++ni) bb[ni] = b2[j0 + wn * 32 + ni * 16 + (lane & 15)];
#pragma unroll
  for (int mi = 0; mi < 4; ++mi)
#pragma unroll
    for (int ni = 0; ni < 2; ++ni) {
      int col = j0 + wn * 32 + ni * 16 + (lane & 15);
#pragma unroll
      for (int r = 0; r < 4; ++r) {
        int row = b0 + wm * 64 + mi * 16 + (lane >> 4) * 4 + r;
        Y2[(size_t)row * 1024 + col] = acc[mi][ni][r] + bb[ni];
      }
    }
}

// ---------------- k3a: partial column stats over Y (2048 x 1024) ----------------
__global__ __launch_bounds__(256) void k3a(const float* __restrict__ Y,
                                           float* __restrict__ psum,
                                           float* __restrict__ psqs) {
  int r0 = blockIdx.x * 32;
  int c = threadIdx.x * 4;
  float s[4] = {}, ss[4] = {};
  for (int r = 0; r < 32; ++r) {
    float4 v = *(const float4*)&Y[(size_t)(r0 + r) * 1024 + c];
    float e[4] = {v.x, v.y, v.z, v.w};
#pragma unroll
    for (int q = 0; q < 4; ++q) {
      s[q] += e[q];
      ss[q] += e[q] * e[q];
    }
  }
#pragma unroll
  for (int q = 0; q < 4; ++q) {
    psum[blockIdx.x * 1024 + c + q] = s[q];
    psqs[blockIdx.x * 1024 + c + q] = ss[q];
  }
}

// ---------------- k4: GEMM3 split-K, fused BN2+ReLU on A ----------------
__global__ __launch_bounds__(256) void k4_gemm3(
    const float* __restrict__ Y2, const float* __restrict__ scale2,
    const float* __restrict__ shift2, const float* __restrict__ W3,
    float* __restrict__ P) {
  __shared__ float As[64][17], Bs[64][17];
  int b0 = blockIdx.x * 64, j0 = blockIdx.y * 64, kz = blockIdx.z;
  int tid = threadIdx.x;
  int tx = tid & 15, ty = tid >> 4;
  int lrow = tid >> 2, lkq = (tid & 3) * 4;
  float c[4][4] = {};
  int kbase = kz * 256;
  for (int k0 = kbase; k0 < kbase + 256; k0 += 16) {
    float4 sc = *(const float4*)&scale2[k0 + lkq];
    float4 sh = *(const float4*)&shift2[k0 + lkq];
    float4 av = *(const float4*)&Y2[(size_t)(b0 + lrow) * 1024 + k0 + lkq];
    As[lrow][lkq + 0] = fmaxf(0.f, av.x * sc.x + sh.x);
    As[lrow][lkq + 1] = fmaxf(0.f, av.y * sc.y + sh.y);
    As[lrow][lkq + 2] = fmaxf(0.f, av.z * sc.z + sh.z);
    As[lrow][lkq + 3] = fmaxf(0.f, av.w * sc.w + sh.w);
    int j = j0 + lrow;
    float4 bv = make_float4(0.f, 0.f, 0.f, 0.f);
    if (j < 150) bv = *(const float4*)&W3[(size_t)j * 1024 + k0 + lkq];
    Bs[lrow][lkq + 0] = bv.x;
    Bs[lrow][lkq + 1] = bv.y;
    Bs[lrow][lkq + 2] = bv.z;
    Bs[lrow][lkq + 3] = bv.w;
    __syncthreads();
#pragma unroll
    for (int k = 0; k < 16; ++k) {
      float a[4], b[4];
#pragma unroll
      for (int i = 0; i < 4; ++i) a[i] = As[ty * 4 + i][k];
#pragma unroll
      for (int jx = 0; jx < 4; ++jx) b[jx] = Bs[tx * 4 + jx][k];
#pragma unroll
      for (int i = 0; i < 4; ++i)
#pragma unroll
        for (int jx = 0; jx < 4; ++jx) c[i][jx] += a[i] * b[jx];
    }
    __syncthreads();
  }
#pragma unroll
  for (int i = 0; i < 4; ++i) {
    int r = b0 + ty * 4 + i;
#pragma unroll
    for (int jx = 0; jx < 4; ++jx) {
      int jj = j0 + tx * 4 + jx;
      if (jj < 150) P[((size_t)kz * 2048 + r) * 150 + jj] = c[i][jx];
    }
  }
}

// ---------------- k5a: reduce split-K partials + b3 -> Y3, partial stats ----------------
__global__ __launch_bounds__(256) void k5a(const float* __restrict__ P,
                                           const float* __restrict__ b3,
                                           float* __restrict__ Y3,
                                           float* __restrict__ psum,
                                           float* __restrict__ psqs) {
  int r0 = blockIdx.x * 32;
  int j = threadIdx.x;
  if (j >= 150) return;
  float bj = b3[j];
  float s = 0.f, ss = 0.f;
  for (int r = 0; r < 32; ++r) {
    size_t base = (size_t)(r0 + r) * 150 + j;
    float v = bj + P[base] + P[base + 2048 * 150] + P[base + 2 * 2048 * 150] +
              P[base + 3 * 2048 * 150];
    Y3[(size_t)(r0 + r) * 150 + j] = v;
    s += v;
    ss += v * v;
  }
  psum[blockIdx.x * 160 + j] = s;
  psqs[blockIdx.x * 160 + j] = ss;
}

__global__ __launch_bounds__(256) void k5b(const float* __restrict__ psum,
                                           const float* __restrict__ psqs,
                                           const float* __restrict__ g3,
                                           const float* __restrict__ be3,
                                           float* __restrict__ scale3,
                                           float* __restrict__ shift3) {
  int j = threadIdx.x;
  if (j >= 150) return;
  float s = 0.f, ss = 0.f;
  for (int p = 0; p < 64; ++p) {
    s += psum[p * 160 + j];
    ss += psqs[p * 160 + j];
  }
  float mu = s * (1.f / 2048.f);
  float var = ss * (1.f / 2048.f) - mu * mu;
  float sc = g3[j] * rsqrtf(var + EPS);
  scale3[j] = sc;
  shift3[j] = be3[j] - mu * sc;
}

// ---------------- k6a: BN3+ReLU + conv chain -> lorentz pre-struct ----------------
// 4 rows per block, one wave per row. Padded LDS arrays -> guard-free taps.
// cf (1x1) folded into ct3. Writes Spre[r][cc] = {s0^2, s1^2, s2^2, s2}.
__global__ __launch_bounds__(256) void k6a(
    const float* __restrict__ Y3, const float* __restrict__ scale3,
    const float* __restrict__ shift3, const float* __restrict__ ct1_w,
    const float* __restrict__ ct1_b, const float* __restrict__ ct2_w,
    const float* __restrict__ ct2_b, const float* __restrict__ ct3_w,
    const float* __restrict__ ct3_b, const float* __restrict__ cf_w,
    const float* __restrict__ cf_b, float* __restrict__ Spre) {
  __shared__ float wt1[32], wb1[4], wt2[80], wb2[4], w3f[20];
  __shared__ float cfb2s;
  __shared__ float h0p[4][160];
  __shared__ float hA[4][4][308];
  __shared__ float hB[4][4][308];
  __shared__ float Srow[4][304];
  int tid = threadIdx.x;
  if (tid < 32) wt1[tid] = ct1_w[tid];
  else if (tid < 36) wb1[tid - 32] = ct1_b[tid - 32];
  else if (tid < 116) wt2[tid - 36] = ct2_w[tid - 36];
  else if (tid < 120) wb2[tid - 116] = ct2_b[tid - 116];
  else if (tid < 140) {
    int i = (tid - 120) / 5, j = (tid - 120) % 5;
    float s = 0.f;
#pragma unroll
    for (int p = 0; p < 4; ++p) s += cf_w[p] * ct3_w[(i * 4 + p) * 5 + j];
    w3f[tid - 120] = s;
  } else if (tid == 140) {
    float s = cf_b[0];
#pragma unroll
    for (int p = 0; p < 4; ++p) s += cf_w[p] * ct3_b[p];
    cfb2s = s;
  }
  int w = tid >> 6;
  int lane = tid & 63;
  int r = blockIdx.x * 4 + w;
  __syncthreads();
  // h0 padded: h0p[2+s] = bn(Y3[r][s]), zeros elsewhere
  for (int i = lane; i < 160; i += 64) {
    int k = i - 2;
    float v = 0.f;
    if (k >= 0 && k < 150)
      v = fmaxf(0.f, Y3[(size_t)r * 150 + k] * scale3[k] + shift3[k]);
    h0p[w][i] = v;
  }
  if (lane < 8) {
    int z = (lane < 2) ? lane : (302 + lane - 2);
#pragma unroll
    for (int o = 0; o < 4; ++o) {
      hA[w][o][z] = 0.f;
      hB[w][o][z] = 0.f;
    }
  }
  __syncthreads();
  // ct1 (stride-2, parity-resolved: 4 taps, no guards)
  for (int t = lane; t < 300; t += 64) {
    int p1 = (t + 3) & 1;
    int base = (t + 3 - p1) >> 1;
    float x0 = h0p[w][2 + base];
    float x1 = h0p[w][1 + base];
    float x2 = h0p[w][base];
    float x3 = h0p[w][base - 1];
#pragma unroll
    for (int o = 0; o < 4; ++o) {
      float acc = wb1[o];
      acc += wt1[o * 8 + p1] * x0;
      acc += wt1[o * 8 + p1 + 2] * x1;
      acc += wt1[o * 8 + p1 + 4] * x2;
      acc += wt1[o * 8 + p1 + 6] * x3;
      hA[w][o][2 + t] = acc;
    }
  }
  __syncthreads();
  // ct2: 4->4, 5 taps, guard-free via padding
  for (int t = lane; t < 300; t += 64) {
#pragma unroll
    for (int o = 0; o < 4; ++o) {
      float acc = wb2[o];
#pragma unroll
      for (int i = 0; i < 4; ++i)
#pragma unroll
        for (int j = 0; j < 5; ++j) acc += wt2[(i * 4 + o) * 5 + j] * hA[w][i][t + 4 - j];
      hB[w][o][2 + t] = acc;
    }
  }
  __syncthreads();
  // ct3 + cf folded: 4->1, 5 taps
  for (int t = lane; t < 300; t += 64) {
    float acc = cfb2s;
#pragma unroll
    for (int i = 0; i < 4; ++i)
#pragma unroll
      for (int j = 0; j < 5; ++j) acc += w3f[i * 5 + j] * hB[w][i][t + 4 - j];
    Srow[w][t] = acc;
  }
  __syncthreads();
  // lorentz pre-struct
  for (int cc = lane; cc < 100; cc += 64) {
    float s0 = Srow[w][3 * cc], s1 = Srow[w][3 * cc + 1], s2 = Srow[w][3 * cc + 2];
    float4 p;
    p.x = s0 * s0;
    p.y = s1 * s1;
    p.z = s2 * s2;
    p.w = s2;
    *(float4*)&Spre[((size_t)r * 100 + cc) * 4] = p;
  }
}

// ---------------- k6b: lorentz via wave-uniform scalar loads ----------------
__global__ __launch_bounds__(320) void k6b(const float* __restrict__ Spre,
                                           float* __restrict__ out) {
  int b = blockIdx.x;
  int l = threadIdx.x;
  float wl = 0.8f + (float)l * (1.0f / 300.0f);
  float w2l = wl * wl;
  float acc = 0.f;
  const float* pp = &Spre[(size_t)b * 400];
#pragma unroll 4
  for (int cc = 0; cc < 100; ++cc) {
    float4 p = *(const float4*)(pp + cc * 4);  // uniform addr -> s_load_dwordx4
    float wp2 = p.x, s1sq = p.y, s2sq = p.z, s2 = p.w;
    float sub1 = s1sq - w2l;
    float t0 = w2l * s2sq;
    float denom = fmaf(sub1, sub1, t0);
    float inv = __builtin_amdgcn_rcpf(denom);
    float tq = wp2 * inv;
    float e1 = tq * sub1;
    float e2 = tq * (wl * s2);
    float m2 = fmaf(e2, e2, e1 * e1);
    float x = fmaxf(0.5f * (m2 + e1), 0.f);
    float n = __builtin_amdgcn_sqrtf(x);
    float kap2 = fmaxf(0.5f * (m2 - e1), 0.f);
    float np1 = n + 1.0f;
    float den2 = fmaf(np1, np1, kap2);
    acc = fmaf(4.0f * n, __builtin_amdgcn_rcpf(den2), acc);
  }
  if (l < 300) out[(size_t)b * 300 + l] = acc;
}

extern "C" void kernel_launch(void* const* d_in, const int* in_sizes, int n_in,
                              void* d_out, int out_size, void* d_ws,
                              size_t ws_size, hipStream_t stream) {
  const float* G = (const float*)d_in[0];
  const float* w1 = (const float*)d_in[1];
  const float* b1 = (const float*)d_in[2];
  const float* g1 = (const float*)d_in[3];
  const float* be1 = (const float*)d_in[4];
  const float* w2 = (const float*)d_in[5];
  const float* b2 = (const float*)d_in[6];
  const float* g2 = (const float*)d_in[7];
  const float* be2 = (const float*)d_in[8];
  const float* w3 = (const float*)d_in[9];
  const float* b3 = (const float*)d_in[10];
  const float* g3 = (const float*)d_in[11];
  const float* be3 = (const float*)d_in[12];
  const float* ct1_w = (const float*)d_in[13];
  const float* ct1_b = (const float*)d_in[14];
  const float* ct2_w = (const float*)d_in[15];
  const float* ct2_b = (const float*)d_in[16];
  const float* ct3_w = (const float*)d_in[17];
  const float* ct3_b = (const float*)d_in[18];
  const float* cf_w = (const float*)d_in[19];
  const float* cf_b = (const float*)d_in[20];
  float* out = (float*)d_out;

  float* ws = (float*)d_ws;
  float* Y2 = ws;                          // [0, 2097152)
  ushort* X1hi = (ushort*)(ws + 2097152);  // 2M ushorts
  ushort* X1lo = (ushort*)(ws + 3145728);  // 2M ushorts
  float* P = ws + 2097152;                 // after k2 (X1 dead): 1,228,800
  float* Spre = ws + 2097152;              // after k5a (P dead): 819,200
  float* Y3 = ws + 3325952;                // 307,200
  float* psum = ws + 3633152;              // 65,536
  float* psqs = ws + 3698688;              // 65,536
  float* scale1 = ws + 4194304;
  float* shift1 = scale1 + 1024;
  float* scale2 = scale1 + 2048;
  float* shift2 = scale1 + 3072;
  float* scale3 = scale1 + 4096;
  float* shift3 = scale1 + 4256;

  k1s<<<64, 256, 0, stream>>>(G, w1, b1, psum, psqs);
  k3b<<<4, 256, 0, stream>>>(psum, psqs, g1, be1, scale1, shift1);
  k1c<<<64, 256, 0, stream>>>(G, w1, b1, scale1, shift1, X1hi, X1lo);
  k2_mfma<<<256, 256, 0, stream>>>(X1hi, X1lo, w2, b2, Y2);
  k3a<<<64, 256, 0, stream>>>(Y2, psum, psqs);
  k3b<<<4, 256, 0, stream>>>(psum, psqs, g2, be2, scale2, shift2);
  k4_gemm3<<<dim3(32, 3, 4), 256, 0, stream>>>(Y2, scale2, shift2, w3, P);
  k5a<<<64, 256, 0, stream>>>(P, b3, Y3, psum, psqs);
  k5b<<<1, 256, 0, stream>>>(psum, psqs, g3, be3, scale3, shift3);
  k6a<<<512, 256, 0, stream>>>(Y3, scale3, shift3, ct1_w, ct1_b, ct2_w, ct2_b,
                               ct3_w, ct3_b, cf_w, cf_b, Spre);
  k6b<<<2048, 320, 0, stream>>>(Spre, out);
}

// Round 4
// 161.564 us; speedup vs baseline: 1.7423x; 1.0035x over previous
//
#include <hip/hip_runtime.h>
#include <hip/hip_bf16.h>

#define EPS 1e-5f

typedef __attribute__((ext_vector_type(8))) short bf16x8;
typedef __attribute__((ext_vector_type(4))) float f32x4;

__device__ __forceinline__ ushort f2bf(float x) {
  __hip_bfloat16 h = __float2bfloat16(x);
  return *reinterpret_cast<ushort*>(&h);
}
__device__ __forceinline__ float bf2f(ushort u) {
  __hip_bfloat16 h;
  *reinterpret_cast<ushort*>(&h) = u;
  return __bfloat162float(h);
}

// ---------------- k1s: layer1 stats (recompute Y1 on the fly) ----------------
__global__ __launch_bounds__(256) void k1s(const float* __restrict__ G,
                                           const float* __restrict__ W1,
                                           const float* __restrict__ b1,
                                           float* __restrict__ psum,
                                           float* __restrict__ psqs) {
  int r0 = blockIdx.x * 32;
  int c = threadIdx.x * 4;
  float w[4][8];
#pragma unroll
  for (int q = 0; q < 4; ++q)
#pragma unroll
    for (int k = 0; k < 8; ++k) w[q][k] = W1[(c + q) * 8 + k];
  float b4[4];
#pragma unroll
  for (int q = 0; q < 4; ++q) b4[q] = b1[c + q];
  float s[4] = {}, ss[4] = {};
  for (int r = 0; r < 32; ++r) {
    const float4 g0 = *(const float4*)&G[(size_t)(r0 + r) * 8];
    const float4 g1 = *(const float4*)&G[(size_t)(r0 + r) * 8 + 4];
    float gr[8] = {g0.x, g0.y, g0.z, g0.w, g1.x, g1.y, g1.z, g1.w};
#pragma unroll
    for (int q = 0; q < 4; ++q) {
      float acc = b4[q];
#pragma unroll
      for (int k = 0; k < 8; ++k) acc += gr[k] * w[q][k];
      s[q] += acc;
      ss[q] += acc * acc;
    }
  }
#pragma unroll
  for (int q = 0; q < 4; ++q) {
    psum[blockIdx.x * 1024 + c + q] = s[q];
    psqs[blockIdx.x * 1024 + c + q] = ss[q];
  }
}

// ---------------- k3b: finalize column stats -> scale/shift ----------------
__global__ __launch_bounds__(256) void k3b(const float* __restrict__ psum,
                                           const float* __restrict__ psqs,
                                           const float* __restrict__ g,
                                           const float* __restrict__ be,
                                           float* __restrict__ scale,
                                           float* __restrict__ shift) {
  int j = blockIdx.x * 256 + threadIdx.x;
  float s = 0.f, ss = 0.f;
  for (int p = 0; p < 64; ++p) {
    s += psum[p * 1024 + j];
    ss += psqs[p * 1024 + j];
  }
  float mu = s * (1.f / 2048.f);
  float var = ss * (1.f / 2048.f) - mu * mu;
  float sc = g[j] * rsqrtf(var + EPS);
  scale[j] = sc;
  shift[j] = be[j] - mu * sc;
}

// ---------------- k1c: recompute Y1, BN+ReLU, split to bf16 hi/lo ----------------
__global__ __launch_bounds__(256) void k1c(
    const float* __restrict__ G, const float* __restrict__ W1,
    const float* __restrict__ b1, const float* __restrict__ scale1,
    const float* __restrict__ shift1, ushort* __restrict__ X1hi,
    ushort* __restrict__ X1lo) {
  int r0 = blockIdx.x * 32;
  int c = threadIdx.x * 4;
  float w[4][8];
#pragma unroll
  for (int q = 0; q < 4; ++q)
#pragma unroll
    for (int k = 0; k < 8; ++k) w[q][k] = W1[(c + q) * 8 + k];
  float b4[4], sc[4], sh[4];
#pragma unroll
  for (int q = 0; q < 4; ++q) {
    b4[q] = b1[c + q];
    sc[q] = scale1[c + q];
    sh[q] = shift1[c + q];
  }
  for (int r = 0; r < 32; ++r) {
    const float4 g0 = *(const float4*)&G[(size_t)(r0 + r) * 8];
    const float4 g1 = *(const float4*)&G[(size_t)(r0 + r) * 8 + 4];
    float gr[8] = {g0.x, g0.y, g0.z, g0.w, g1.x, g1.y, g1.z, g1.w};
    ushort hs[4], ls[4];
#pragma unroll
    for (int q = 0; q < 4; ++q) {
      float acc = b4[q];
#pragma unroll
      for (int k = 0; k < 8; ++k) acc += gr[k] * w[q][k];
      float x = fmaxf(0.f, acc * sc[q] + sh[q]);
      ushort h = f2bf(x);
      float hf = bf2f(h);
      hs[q] = h;
      ls[q] = f2bf(x - hf);
    }
    size_t o = (size_t)(r0 + r) * 1024 + c;
    *(ushort4*)&X1hi[o] = make_ushort4(hs[0], hs[1], hs[2], hs[3]);
    *(ushort4*)&X1lo[o] = make_ushort4(ls[0], ls[1], ls[2], ls[3]);
  }
}

// ---------------- k2: MFMA bf16 hi/lo GEMM2 ----------------
__global__ __launch_bounds__(256) void k2_mfma(
    const ushort* __restrict__ X1hi, const ushort* __restrict__ X1lo,
    const float* __restrict__ W2, const float* __restrict__ b2,
    float* __restrict__ Y2) {
  __shared__ short lAhi[128 * 64], lAlo[128 * 64];
  __shared__ short lBhi[64 * 64], lBlo[64 * 64];
  int id = blockIdx.x;
  int xcd = id & 7, slot = id >> 3;
  int g = slot >> 4, wi = slot & 15;
  int bx = (xcd & 3) * 4 + (wi & 3);
  int by = ((xcd >> 2) * 2 + g) * 4 + (wi >> 2);
  int b0 = bx * 128, j0 = by * 64;
  int tid = threadIdx.x;
  int lane = tid & 63, wave = tid >> 6;
  int wm = wave >> 1, wn = wave & 1;
  int brow = tid >> 2, bkq = tid & 3;
  f32x4 acc[4][2] = {};
  for (int k0 = 0; k0 < 1024; k0 += 64) {
#pragma unroll
    for (int i = 0; i < 4; ++i) {
      int chunk = tid * 4 + i;
      int row = chunk >> 3, c = chunk & 7;
      size_t go = (size_t)(b0 + row) * 1024 + k0 + c * 8;
      bf16x8 vh = *(const bf16x8*)&X1hi[go];
      bf16x8 vl = *(const bf16x8*)&X1lo[go];
      int d = row * 64 + ((c ^ (row & 7)) << 3);
      *(bf16x8*)&lAhi[d] = vh;
      *(bf16x8*)&lAlo[d] = vl;
    }
    {
      const float* src = &W2[(size_t)(j0 + brow) * 1024 + k0 + bkq * 16];
      float4 f0 = *(const float4*)(src);
      float4 f1 = *(const float4*)(src + 4);
      float4 f2 = *(const float4*)(src + 8);
      float4 f3 = *(const float4*)(src + 12);
      float v[16] = {f0.x, f0.y, f0.z, f0.w, f1.x, f1.y, f1.z, f1.w,
                     f2.x, f2.y, f2.z, f2.w, f3.x, f3.y, f3.z, f3.w};
      bf16x8 h0, l0, h1, l1;
#pragma unroll
      for (int e = 0; e < 8; ++e) {
        ushort h = f2bf(v[e]);
        h0[e] = (short)h;
        l0[e] = (short)f2bf(v[e] - bf2f(h));
      }
#pragma unroll
      for (int e = 0; e < 8; ++e) {
        ushort h = f2bf(v[8 + e]);
        h1[e] = (short)h;
        l1[e] = (short)f2bf(v[8 + e] - bf2f(h));
      }
      int c0 = bkq * 2, c1 = bkq * 2 + 1;
      int d0 = brow * 64 + ((c0 ^ (brow & 7)) << 3);
      int d1 = brow * 64 + ((c1 ^ (brow & 7)) << 3);
      *(bf16x8*)&lBhi[d0] = h0;
      *(bf16x8*)&lBlo[d0] = l0;
      *(bf16x8*)&lBhi[d1] = h1;
      *(bf16x8*)&lBlo[d1] = l1;
    }
    __syncthreads();
#pragma unroll
    for (int kk = 0; kk < 2; ++kk) {
      bf16x8 ah[4], al[4], bh[2], bl[2];
#pragma unroll
      for (int mi = 0; mi < 4; ++mi) {
        int r = wm * 64 + mi * 16 + (lane & 15);
        int cc = (((kk << 2) + (lane >> 4)) ^ (r & 7)) << 3;
        ah[mi] = *(const bf16x8*)&lAhi[r * 64 + cc];
        al[mi] = *(const bf16x8*)&lAlo[r * 64 + cc];
      }
#pragma unroll
      for (int ni = 0; ni < 2; ++ni) {
        int r = wn * 32 + ni * 16 + (lane & 15);
        int cc = (((kk << 2) + (lane >> 4)) ^ (r & 7)) << 3;
        bh[ni] = *(const bf16x8*)&lBhi[r * 64 + cc];
        bl[ni] = *(const bf16x8*)&lBlo[r * 64 + cc];
      }
#pragma unroll
      for (int mi = 0; mi < 4; ++mi)
#pragma unroll
        for (int ni = 0; ni < 2; ++ni) {
          acc[mi][ni] = __builtin_amdgcn_mfma_f32_16x16x32_bf16(
              ah[mi], bh[ni], acc[mi][ni], 0, 0, 0);
          acc[mi][ni] = __builtin_amdgcn_mfma_f32_16x16x32_bf16(
              al[mi], bh[ni], acc[mi][ni], 0, 0, 0);
          acc[mi][ni] = __builtin_amdgcn_mfma_f32_16x16x32_bf16(
              ah[mi], bl[ni], acc[mi][ni], 0, 0, 0);
        }
    }
    __syncthreads();
  }
  float bb[2];
#pragma unroll
  for (int ni = 0; ni < 2; ++ni) bb[ni] = b2[j0 + wn * 32 + ni * 16 + (lane & 15)];
#pragma unroll
  for (int mi = 0; mi < 4; ++mi)
#pragma unroll
    for (int ni = 0; ni < 2; ++ni) {
      int col = j0 + wn * 32 + ni * 16 + (lane & 15);
#pragma unroll
      for (int r = 0; r < 4; ++r) {
        int row = b0 + wm * 64 + mi * 16 + (lane >> 4) * 4 + r;
        Y2[(size_t)row * 1024 + col] = acc[mi][ni][r] + bb[ni];
      }
    }
}

// ---------------- k3a: partial column stats over Y (2048 x 1024) ----------------
__global__ __launch_bounds__(256) void k3a(const float* __restrict__ Y,
                                           float* __restrict__ psum,
                                           float* __restrict__ psqs) {
  int r0 = blockIdx.x * 32;
  int c = threadIdx.x * 4;
  float s[4] = {}, ss[4] = {};
  for (int r = 0; r < 32; ++r) {
    float4 v = *(const float4*)&Y[(size_t)(r0 + r) * 1024 + c];
    float e[4] = {v.x, v.y, v.z, v.w};
#pragma unroll
    for (int q = 0; q < 4; ++q) {
      s[q] += e[q];
      ss[q] += e[q] * e[q];
    }
  }
#pragma unroll
  for (int q = 0; q < 4; ++q) {
    psum[blockIdx.x * 1024 + c + q] = s[q];
    psqs[blockIdx.x * 1024 + c + q] = ss[q];
  }
}

// ---------------- k4: GEMM3 split-K, fused BN2+ReLU on A ----------------
// tile 32(M) x 64(N), K-slice 256. grid (64, 3, 4) = 768 blocks.
__global__ __launch_bounds__(256) void k4_gemm3(
    const float* __restrict__ Y2, const float* __restrict__ scale2,
    const float* __restrict__ shift2, const float* __restrict__ W3,
    float* __restrict__ P) {
  __shared__ float As[32][17], Bs[64][17];
  int b0 = blockIdx.x * 32, j0 = blockIdx.y * 64, kz = blockIdx.z;
  int tid = threadIdx.x;
  int tx = tid & 15, ty = tid >> 4;
  int arow = tid >> 3, akq = (tid & 7) * 2;   // A: 32 rows x 16 k
  int brow = tid >> 2, bkq = (tid & 3) * 4;   // B: 64 rows x 16 k
  float c[2][4] = {};
  int kbase = kz * 256;
  int jb = j0 + brow;
  for (int k0 = kbase; k0 < kbase + 256; k0 += 16) {
    float2 sc = *(const float2*)&scale2[k0 + akq];
    float2 sh = *(const float2*)&shift2[k0 + akq];
    float2 av = *(const float2*)&Y2[(size_t)(b0 + arow) * 1024 + k0 + akq];
    As[arow][akq + 0] = fmaxf(0.f, av.x * sc.x + sh.x);
    As[arow][akq + 1] = fmaxf(0.f, av.y * sc.y + sh.y);
    float4 bv = make_float4(0.f, 0.f, 0.f, 0.f);
    if (jb < 150) bv = *(const float4*)&W3[(size_t)jb * 1024 + k0 + bkq];
    Bs[brow][bkq + 0] = bv.x;
    Bs[brow][bkq + 1] = bv.y;
    Bs[brow][bkq + 2] = bv.z;
    Bs[brow][bkq + 3] = bv.w;
    __syncthreads();
#pragma unroll
    for (int k = 0; k < 16; ++k) {
      float a[2], b[4];
#pragma unroll
      for (int i = 0; i < 2; ++i) a[i] = As[ty * 2 + i][k];
#pragma unroll
      for (int jx = 0; jx < 4; ++jx) b[jx] = Bs[tx * 4 + jx][k];
#pragma unroll
      for (int i = 0; i < 2; ++i)
#pragma unroll
        for (int jx = 0; jx < 4; ++jx) c[i][jx] += a[i] * b[jx];
    }
    __syncthreads();
  }
#pragma unroll
  for (int i = 0; i < 2; ++i) {
    int r = b0 + ty * 2 + i;
#pragma unroll
    for (int jx = 0; jx < 4; ++jx) {
      int jj = j0 + tx * 4 + jx;
      if (jj < 150) P[((size_t)kz * 2048 + r) * 150 + jj] = c[i][jx];
    }
  }
}

// ---------------- k5a: reduce split-K partials + b3 -> Y3, partial stats ----------------
__global__ __launch_bounds__(256) void k5a(const float* __restrict__ P,
                                           const float* __restrict__ b3,
                                           float* __restrict__ Y3,
                                           float* __restrict__ psum,
                                           float* __restrict__ psqs) {
  int r0 = blockIdx.x * 32;
  int j = threadIdx.x;
  if (j >= 150) return;
  float bj = b3[j];
  float s = 0.f, ss = 0.f;
  for (int r = 0; r < 32; ++r) {
    size_t base = (size_t)(r0 + r) * 150 + j;
    float v = bj + P[base] + P[base + 2048 * 150] + P[base + 2 * 2048 * 150] +
              P[base + 3 * 2048 * 150];
    Y3[(size_t)(r0 + r) * 150 + j] = v;
    s += v;
    ss += v * v;
  }
  psum[blockIdx.x * 160 + j] = s;
  psqs[blockIdx.x * 160 + j] = ss;
}

__global__ __launch_bounds__(256) void k5b(const float* __restrict__ psum,
                                           const float* __restrict__ psqs,
                                           const float* __restrict__ g3,
                                           const float* __restrict__ be3,
                                           float* __restrict__ scale3,
                                           float* __restrict__ shift3) {
  int j = threadIdx.x;
  if (j >= 150) return;
  float s = 0.f, ss = 0.f;
  for (int p = 0; p < 64; ++p) {
    s += psum[p * 160 + j];
    ss += psqs[p * 160 + j];
  }
  float mu = s * (1.f / 2048.f);
  float var = ss * (1.f / 2048.f) - mu * mu;
  float sc = g3[j] * rsqrtf(var + EPS);
  scale3[j] = sc;
  shift3[j] = be3[j] - mu * sc;
}

// ---------------- k6a: BN3+ReLU + conv chain -> lorentz pre-struct ----------------
__global__ __launch_bounds__(256) void k6a(
    const float* __restrict__ Y3, const float* __restrict__ scale3,
    const float* __restrict__ shift3, const float* __restrict__ ct1_w,
    const float* __restrict__ ct1_b, const float* __restrict__ ct2_w,
    const float* __restrict__ ct2_b, const float* __restrict__ ct3_w,
    const float* __restrict__ ct3_b, const float* __restrict__ cf_w,
    const float* __restrict__ cf_b, float* __restrict__ Spre) {
  __shared__ float wt1[32], wb1[4], wt2[80], wb2[4], w3f[20];
  __shared__ float cfb2s;
  __shared__ float h0p[4][160];
  __shared__ float hA[4][4][308];
  __shared__ float hB[4][4][308];
  __shared__ float Srow[4][304];
  int tid = threadIdx.x;
  if (tid < 32) wt1[tid] = ct1_w[tid];
  else if (tid < 36) wb1[tid - 32] = ct1_b[tid - 32];
  else if (tid < 116) wt2[tid - 36] = ct2_w[tid - 36];
  else if (tid < 120) wb2[tid - 116] = ct2_b[tid - 116];
  else if (tid < 140) {
    int i = (tid - 120) / 5, j = (tid - 120) % 5;
    float s = 0.f;
#pragma unroll
    for (int p = 0; p < 4; ++p) s += cf_w[p] * ct3_w[(i * 4 + p) * 5 + j];
    w3f[tid - 120] = s;
  } else if (tid == 140) {
    float s = cf_b[0];
#pragma unroll
    for (int p = 0; p < 4; ++p) s += cf_w[p] * ct3_b[p];
    cfb2s = s;
  }
  int w = tid >> 6;
  int lane = tid & 63;
  int r = blockIdx.x * 4 + w;
  __syncthreads();
  for (int i = lane; i < 160; i += 64) {
    int k = i - 2;
    float v = 0.f;
    if (k >= 0 && k < 150)
      v = fmaxf(0.f, Y3[(size_t)r * 150 + k] * scale3[k] + shift3[k]);
    h0p[w][i] = v;
  }
  if (lane < 8) {
    int z = (lane < 2) ? lane : (302 + lane - 2);
#pragma unroll
    for (int o = 0; o < 4; ++o) {
      hA[w][o][z] = 0.f;
      hB[w][o][z] = 0.f;
    }
  }
  __syncthreads();
  for (int t = lane; t < 300; t += 64) {
    int p1 = (t + 3) & 1;
    int base = (t + 3 - p1) >> 1;
    float x0 = h0p[w][2 + base];
    float x1 = h0p[w][1 + base];
    float x2 = h0p[w][base];
    float x3 = h0p[w][base - 1];
#pragma unroll
    for (int o = 0; o < 4; ++o) {
      float acc = wb1[o];
      acc += wt1[o * 8 + p1] * x0;
      acc += wt1[o * 8 + p1 + 2] * x1;
      acc += wt1[o * 8 + p1 + 4] * x2;
      acc += wt1[o * 8 + p1 + 6] * x3;
      hA[w][o][2 + t] = acc;
    }
  }
  __syncthreads();
  for (int t = lane; t < 300; t += 64) {
#pragma unroll
    for (int o = 0; o < 4; ++o) {
      float acc = wb2[o];
#pragma unroll
      for (int i = 0; i < 4; ++i)
#pragma unroll
        for (int j = 0; j < 5; ++j) acc += wt2[(i * 4 + o) * 5 + j] * hA[w][i][t + 4 - j];
      hB[w][o][2 + t] = acc;
    }
  }
  __syncthreads();
  for (int t = lane; t < 300; t += 64) {
    float acc = cfb2s;
#pragma unroll
    for (int i = 0; i < 4; ++i)
#pragma unroll
      for (int j = 0; j < 5; ++j) acc += w3f[i * 5 + j] * hB[w][i][t + 4 - j];
    Srow[w][t] = acc;
  }
  __syncthreads();
  for (int cc = lane; cc < 100; cc += 64) {
    float s0 = Srow[w][3 * cc], s1 = Srow[w][3 * cc + 1], s2 = Srow[w][3 * cc + 2];
    float4 p;
    p.x = s0 * s0;
    p.y = s1 * s1;
    p.z = s2 * s2;
    p.w = 0.f;
    *(float4*)&Spre[((size_t)r * 100 + cc) * 4] = p;
  }
}

// ---------------- k6b: lorentz, cc-split x4, wave-uniform scalar loads ----------------
// m = 0.5*wp2^2/denom identity removes e2 entirely.
__global__ __launch_bounds__(320) void k6b(const float* __restrict__ Spre,
                                           float* __restrict__ out) {
  int b = blockIdx.x;
  int l = threadIdx.x;
  float wl = 0.8f + (float)l * (1.0f / 300.0f);
  float w2l = wl * wl;
  float acc = 0.f;
  const float4* pp = (const float4*)&Spre[(size_t)b * 400] + blockIdx.y * 25;
#pragma unroll 5
  for (int cc = 0; cc < 25; ++cc) {
    float4 p = pp[cc];  // uniform addr -> scalar load
    float wp2 = p.x, s1sq = p.y, s2sq = p.z;
    float sub1 = s1sq - w2l;
    float denom = fmaf(sub1, sub1, w2l * s2sq);
    float inv = __builtin_amdgcn_rcpf(denom);
    float u = wp2 * inv;
    float tp = u * (wp2 + sub1);   // = 2m + e1
    float tm = u * (wp2 - sub1);   // = 2m - e1
    float n = 0.70710678f * __builtin_amdgcn_sqrtf(fmaxf(tp, 0.f));
    float np1 = n + 1.0f;
    float den2 = fmaf(np1, np1, 0.5f * fmaxf(tm, 0.f));
    acc = fmaf(4.0f * n, __builtin_amdgcn_rcpf(den2), acc);
  }
  if (l < 300) atomicAdd(&out[(size_t)b * 300 + l], acc);
}

extern "C" void kernel_launch(void* const* d_in, const int* in_sizes, int n_in,
                              void* d_out, int out_size, void* d_ws,
                              size_t ws_size, hipStream_t stream) {
  const float* G = (const float*)d_in[0];
  const float* w1 = (const float*)d_in[1];
  const float* b1 = (const float*)d_in[2];
  const float* g1 = (const float*)d_in[3];
  const float* be1 = (const float*)d_in[4];
  const float* w2 = (const float*)d_in[5];
  const float* b2 = (const float*)d_in[6];
  const float* g2 = (const float*)d_in[7];
  const float* be2 = (const float*)d_in[8];
  const float* w3 = (const float*)d_in[9];
  const float* b3 = (const float*)d_in[10];
  const float* g3 = (const float*)d_in[11];
  const float* be3 = (const float*)d_in[12];
  const float* ct1_w = (const float*)d_in[13];
  const float* ct1_b = (const float*)d_in[14];
  const float* ct2_w = (const float*)d_in[15];
  const float* ct2_b = (const float*)d_in[16];
  const float* ct3_w = (const float*)d_in[17];
  const float* ct3_b = (const float*)d_in[18];
  const float* cf_w = (const float*)d_in[19];
  const float* cf_b = (const float*)d_in[20];
  float* out = (float*)d_out;

  float* ws = (float*)d_ws;
  float* Y2 = ws;                          // [0, 2097152)
  ushort* X1hi = (ushort*)(ws + 2097152);  // 2M ushorts
  ushort* X1lo = (ushort*)(ws + 3145728);  // 2M ushorts
  float* P = ws + 2097152;                 // after k2 (X1 dead): 1,228,800
  float* Spre = ws + 2097152;              // after k5a (P dead): 819,200
  float* Y3 = ws + 3325952;                // 307,200
  float* psum = ws + 3633152;              // 65,536
  float* psqs = ws + 3698688;              // 65,536
  float* scale1 = ws + 4194304;
  float* shift1 = scale1 + 1024;
  float* scale2 = scale1 + 2048;
  float* shift2 = scale1 + 3072;
  float* scale3 = scale1 + 4096;
  float* shift3 = scale1 + 4256;

  k1s<<<64, 256, 0, stream>>>(G, w1, b1, psum, psqs);
  k3b<<<4, 256, 0, stream>>>(psum, psqs, g1, be1, scale1, shift1);
  k1c<<<64, 256, 0, stream>>>(G, w1, b1, scale1, shift1, X1hi, X1lo);
  k2_mfma<<<256, 256, 0, stream>>>(X1hi, X1lo, w2, b2, Y2);
  k3a<<<64, 256, 0, stream>>>(Y2, psum, psqs);
  k3b<<<4, 256, 0, stream>>>(psum, psqs, g2, be2, scale2, shift2);
  k4_gemm3<<<dim3(64, 3, 4), 256, 0, stream>>>(Y2, scale2, shift2, w3, P);
  k5a<<<64, 256, 0, stream>>>(P, b3, Y3, psum, psqs);
  k5b<<<1, 256, 0, stream>>>(psum, psqs, g3, be3, scale3, shift3);
  k6a<<<512, 256, 0, stream>>>(Y3, scale3, shift3, ct1_w, ct1_b, ct2_w, ct2_b,
                               ct3_w, ct3_b, cf_w, cf_b, Spre);
  hipMemsetAsync(out, 0, (size_t)out_size * sizeof(float), stream);
  k6b<<<dim3(2048, 4), 320, 0, stream>>>(Spre, out);
}